// Round 7
// baseline (457.089 us; speedup 1.0000x reference)
//
#include <hip/hip_runtime.h>
#include <cstdint>

// ---------------------------------------------------------------------------
// TinyViT block on gfx950. Round 7: LDS-free direct-load GEMM. MFMA A/B
// fragments are loaded straight from global (each 64B line fully consumed by
// one quad-group -> no waste), eliminating LDS staging, barriers, and bank
// conflicts for the short-K GEMMs. K is a template constant.
// ---------------------------------------------------------------------------

typedef __bf16 bf16x8 __attribute__((ext_vector_type(8)));
typedef __bf16 bf16x4 __attribute__((ext_vector_type(4)));
typedef float  f32x4  __attribute__((ext_vector_type(4)));

#define DIM_    384
#define QKVD    1152
#define HIDD    1536
#define NTOK    49
#define NWIN    400
#define MPAD    19712     /* 154*128 */
#define MREAL   19600
#define TOKENS  16384     /* 4*4096 */
#define SCALE_  0.17677669529663689f
#define EPS_    1e-5f

// prep job block ranges (256 threads each)
#define B_LN1   9856      /* 19712 tokens, 2 per block        */
#define B_QKV   1728      /* 442368 elems                     */
#define B_PROJ  576       /* 147456                           */
#define B_FC1   2304      /* 589824                           */
#define B_FC2   2304      /* 589824                           */
#define B_CONV  14        /* 3456                             */
#define B_BIAS  192       /* 49152                            */
#define B_TOTAL (B_LN1 + B_QKV + B_PROJ + B_FC1 + B_FC2 + B_CONV + B_BIAS)

// tanh-form GELU via sigmoid + fast rcp
__device__ __forceinline__ float gelu_fast(float v) {
  float t2 = v * (1.5957691216057308f + 0.07135481627f * v * v);
  return v * __builtin_amdgcn_rcpf(1.f + __expf(-t2));
}

// ---------------------------------------------------------------------------
// Fused prep: LN1+window partition, 4 weight transposes, conv-w transpose,
// attention bias table. One kernel, block-range dispatch, 256 threads.
// ---------------------------------------------------------------------------
__global__ __launch_bounds__(256) void prep_all(
    const float* __restrict__ x, const float* __restrict__ ln1_g,
    const float* __restrict__ ln1_b, __bf16* __restrict__ xn,
    const float* __restrict__ qkv_w,  __bf16* __restrict__ wqkv,
    const float* __restrict__ proj_w, __bf16* __restrict__ wproj,
    const float* __restrict__ fc1_w,  __bf16* __restrict__ wfc1,
    const float* __restrict__ fc2_w,  __bf16* __restrict__ wfc2,
    const float* __restrict__ conv_w, float* __restrict__ wconv,
    const float* __restrict__ attn_b, float* __restrict__ bm) {
  int b = blockIdx.x;
  int tid = threadIdx.x;

  if (b < B_LN1) {
    // ---- LN1 + window partition: 2 tokens per block, no early returns ----
    int sub = tid >> 7, tl = tid & 127;
    int t = b * 2 + sub;                       // 0..19711
    __bf16* orow = xn + (long)t * DIM_;
    int kind;                                  // 0=valid 1=bet-pad 2=zero-pad
    int bb = 0, r = 0, c = 0;
    if (t >= MREAL) kind = 2;
    else {
      int win = t / NTOK, tt = t % NTOK;
      bb = win / 100;
      int rem = win % 100;
      r = (rem / 10) * 7 + tt / 7;
      c = (rem % 10) * 7 + tt % 7;
      kind = (r >= 64 || c >= 64) ? 1 : 0;
    }
    float v0 = 0.f, v1 = 0.f, v2 = 0.f;
    if (kind == 0) {
      const float* xr = x + ((long)bb * 4096 + r * 64 + c) * DIM_;
      v0 = xr[tl]; v1 = xr[tl + 128]; v2 = xr[tl + 256];
    }
    float s = v0 + v1 + v2, s2 = v0 * v0 + v1 * v1 + v2 * v2;
    for (int off = 32; off; off >>= 1) { s += __shfl_down(s, off); s2 += __shfl_down(s2, off); }
    __shared__ float red[2][4];
    if ((tl & 63) == 0) { red[sub][tl >> 6] = s; red[sub][2 + (tl >> 6)] = s2; }
    __syncthreads();
    float S = red[sub][0] + red[sub][1], S2 = red[sub][2] + red[sub][3];
    float m  = S * (1.f / DIM_);
    float rs = rsqrtf(S2 * (1.f / DIM_) - m * m + EPS_);
    if (kind == 0) {
      orow[tl]       = (__bf16)((v0 - m) * rs * ln1_g[tl]       + ln1_b[tl]);
      orow[tl + 128] = (__bf16)((v1 - m) * rs * ln1_g[tl + 128] + ln1_b[tl + 128]);
      orow[tl + 256] = (__bf16)((v2 - m) * rs * ln1_g[tl + 256] + ln1_b[tl + 256]);
    } else if (kind == 1) {
      orow[tl]       = (__bf16)ln1_b[tl];
      orow[tl + 128] = (__bf16)ln1_b[tl + 128];
      orow[tl + 256] = (__bf16)ln1_b[tl + 256];
    } else {
      orow[tl] = (__bf16)0.f; orow[tl + 128] = (__bf16)0.f; orow[tl + 256] = (__bf16)0.f;
    }
    return;
  }
  b -= B_LN1;
  if (b < B_QKV) {               // qkv_w (384x1152) -> wqkv (1152x384)
    int id = b * 256 + tid;      // < 442368 exactly
    int k = id % DIM_; int n = id / DIM_;
    wqkv[id] = (__bf16)qkv_w[(long)k * QKVD + n];
    return;
  }
  b -= B_QKV;
  if (b < B_PROJ) {              // proj_w (384x384) -> wproj (384x384)^T
    int id = b * 256 + tid;
    int k = id % DIM_; int n = id / DIM_;
    wproj[id] = (__bf16)proj_w[(long)k * DIM_ + n];
    return;
  }
  b -= B_PROJ;
  if (b < B_FC1) {               // fc1_w (384x1536) -> wfc1 (1536x384)
    int id = b * 256 + tid;
    int k = id % DIM_; int n = id / DIM_;
    wfc1[id] = (__bf16)fc1_w[(long)k * HIDD + n];
    return;
  }
  b -= B_FC1;
  if (b < B_FC2) {               // fc2_w (1536x384) -> wfc2 (384x1536)
    int id = b * 256 + tid;
    int k = id % HIDD; int n = id / HIDD;
    wfc2[id] = (__bf16)fc2_w[(long)k * DIM_ + n];
    return;
  }
  b -= B_FC2;
  if (b < B_CONV) {              // conv_w [384][9] -> wconv [9][384]
    int id = b * 256 + tid;
    if (id < 3456) {
      int ch = id / 9, k = id % 9;
      wconv[k * DIM_ + ch] = conv_w[id];
    }
    return;
  }
  b -= B_CONV;
  {                              // bias table bm[12][64][64]
    int id = b * 256 + tid;      // < 49152
    int h = id >> 12, q = (id >> 6) & 63, kk = id & 63;
    float v;
    if (kk >= NTOK)      v = -1e30f;
    else if (q >= NTOK)  v = 0.f;
    else {
      int idx = abs(q / 7 - kk / 7) * 7 + abs(q % 7 - kk % 7);
      v = attn_b[h * NTOK + idx];
    }
    bm[id] = v;
  }
}

// ---------------------------------------------------------------------------
// Fused depthwise 3x3 conv + BN + LN2. Block = 4 pixels x 96 lanes (384 thr).
// ---------------------------------------------------------------------------
__global__ __launch_bounds__(384) void conv_bn_ln2(
    const float* __restrict__ x1, const float* __restrict__ wT,
    const float* __restrict__ bng, const float* __restrict__ bnb,
    const float* __restrict__ mean, const float* __restrict__ var,
    const float* __restrict__ g2, const float* __restrict__ b2,
    float* __restrict__ x2, __bf16* __restrict__ xln2) {
  int tid = threadIdx.x;
  int p = tid / 96, g = tid % 96;
  int pix = blockIdx.x * 4 + p;            // 0..16383
  int bb = pix >> 12, rc = pix & 4095;
  int r = rc >> 6, c = rc & 63;
  int ch = g << 2;

  f32x4 acc = (f32x4){0.f, 0.f, 0.f, 0.f};
  #pragma unroll
  for (int dr = -1; dr <= 1; dr++) {
    int rr = r + dr;
    if (rr < 0 || rr >= 64) continue;
    #pragma unroll
    for (int dc = -1; dc <= 1; dc++) {
      int cc = c + dc;
      if (cc < 0 || cc >= 64) continue;
      f32x4 xv = *(const f32x4*)(x1 + ((long)bb * 4096 + rr * 64 + cc) * DIM_ + ch);
      f32x4 wv = *(const f32x4*)(wT + ((dr + 1) * 3 + (dc + 1)) * DIM_ + ch);
      acc += xv * wv;
    }
  }

  f32x4 gv = *(const f32x4*)(bng + ch);
  f32x4 vv = *(const f32x4*)(var + ch);
  f32x4 mv = *(const f32x4*)(mean + ch);
  f32x4 bv = *(const f32x4*)(bnb + ch);
  f32x4 y;
  #pragma unroll
  for (int j = 0; j < 4; j++) {
    float sc = gv[j] * rsqrtf(vv[j] + EPS_);
    y[j] = acc[j] * sc + (bv[j] - mv[j] * sc);
  }
  *(f32x4*)(x2 + (long)pix * DIM_ + ch) = y;

  __shared__ float pS[4][96], pS2[4][96], mS[4], rS[4];
  pS[p][g]  = y[0] + y[1] + y[2] + y[3];
  pS2[p][g] = y[0] * y[0] + y[1] * y[1] + y[2] * y[2] + y[3] * y[3];
  __syncthreads();
  if (g < 32) {
    float a  = pS[p][g]  + pS[p][g + 32]  + pS[p][g + 64];
    float a2 = pS2[p][g] + pS2[p][g + 32] + pS2[p][g + 64];
    #pragma unroll
    for (int off = 1; off < 32; off <<= 1) {
      a  += __shfl_xor(a, off);
      a2 += __shfl_xor(a2, off);
    }
    if (g == 0) {
      float m = a * (1.f / DIM_);
      mS[p] = m;
      rS[p] = rsqrtf(a2 * (1.f / DIM_) - m * m + EPS_);
    }
  }
  __syncthreads();
  float m = mS[p], rs = rS[p];
  f32x4 gg = *(const f32x4*)(g2 + ch);
  f32x4 b2v = *(const f32x4*)(b2 + ch);
  bf16x4 ov;
  #pragma unroll
  for (int j = 0; j < 4; j++) ov[j] = (__bf16)((y[j] - m) * rs * gg[j] + b2v[j]);
  *(bf16x4*)(xln2 + (long)pix * DIM_ + ch) = ov;
}

// ---------------------------------------------------------------------------
// MFMA attention: one 64-thread block per (window, head). 4800 blocks.
// ---------------------------------------------------------------------------
__global__ __launch_bounds__(64) void attn_mfma(const __bf16* __restrict__ qkv,
                                                const float* __restrict__ bm,
                                                __bf16* __restrict__ o) {
  int blk = blockIdx.x;
  int win = blk / 12, h = blk % 12;
  int lane = threadIdx.x;
  int quad = lane >> 4, l16 = lane & 15;

  __shared__ __align__(16) __bf16 Vt[32][72];   // Vt[d][kk]
  __shared__ __align__(16) __bf16 P[64][72];    // P[q][kk]

  const __bf16* base = qkv + (long)win * NTOK * QKVD + h * 96;

  bf16x8 qf[4], kf[4];
  #pragma unroll
  for (int t = 0; t < 4; t++) {
    const __bf16* rp = base + (long)(t * 16 + l16) * QKVD + quad * 8;
    qf[t] = *(const bf16x8*)(rp);
    kf[t] = *(const bf16x8*)(rp + 32);
  }
  {
    const __bf16* vp = base + (long)lane * QKVD + 64;
    bf16x8 vv[4];
    #pragma unroll
    for (int i = 0; i < 4; i++) vv[i] = *(const bf16x8*)(vp + i * 8);
    #pragma unroll
    for (int i = 0; i < 4; i++)
      #pragma unroll
      for (int j = 0; j < 8; j++) Vt[i * 8 + j][lane] = vv[i][j];
  }

  f32x4 S[4][4];
  #pragma unroll
  for (int i = 0; i < 4; i++)
    #pragma unroll
    for (int j = 0; j < 4; j++) S[i][j] = (f32x4){0.f, 0.f, 0.f, 0.f};
  #pragma unroll
  for (int mt = 0; mt < 4; mt++)
    #pragma unroll
    for (int nt = 0; nt < 4; nt++)
      S[mt][nt] = __builtin_amdgcn_mfma_f32_16x16x32_bf16(qf[mt], kf[nt], S[mt][nt], 0, 0, 0);

  const float* bmh = bm + h * 4096;
  #pragma unroll
  for (int mt = 0; mt < 4; mt++)
    #pragma unroll
    for (int r = 0; r < 4; r++) {
      int q = mt * 16 + quad * 4 + r;
      #pragma unroll
      for (int nt = 0; nt < 4; nt++)
        S[mt][nt][r] = S[mt][nt][r] * SCALE_ + bmh[q * 64 + nt * 16 + l16];
    }

  #pragma unroll
  for (int mt = 0; mt < 4; mt++)
    #pragma unroll
    for (int r = 0; r < 4; r++) {
      float mx = fmaxf(fmaxf(S[mt][0][r], S[mt][1][r]), fmaxf(S[mt][2][r], S[mt][3][r]));
      #pragma unroll
      for (int off = 1; off < 16; off <<= 1) mx = fmaxf(mx, __shfl_xor(mx, off));
      float sum = 0.f;
      #pragma unroll
      for (int nt = 0; nt < 4; nt++) {
        float e = __expf(S[mt][nt][r] - mx);
        S[mt][nt][r] = e;
        sum += e;
      }
      #pragma unroll
      for (int off = 1; off < 16; off <<= 1) sum += __shfl_xor(sum, off);
      float inv = 1.f / sum;
      #pragma unroll
      for (int nt = 0; nt < 4; nt++) S[mt][nt][r] *= inv;
    }

  #pragma unroll
  for (int mt = 0; mt < 4; mt++)
    #pragma unroll
    for (int r = 0; r < 4; r++) {
      int q = mt * 16 + quad * 4 + r;
      #pragma unroll
      for (int nt = 0; nt < 4; nt++)
        P[q][nt * 16 + l16] = (__bf16)S[mt][nt][r];
    }
  __syncthreads();

  f32x4 O[4][2];
  #pragma unroll
  for (int i = 0; i < 4; i++)
    #pragma unroll
    for (int j = 0; j < 2; j++) O[i][j] = (f32x4){0.f, 0.f, 0.f, 0.f};
  #pragma unroll
  for (int kt = 0; kt < 2; kt++) {
    bf16x8 pf[4], vf[2];
    #pragma unroll
    for (int mt = 0; mt < 4; mt++)
      pf[mt] = *(const bf16x8*)(&P[mt * 16 + l16][kt * 32 + quad * 8]);
    #pragma unroll
    for (int nt = 0; nt < 2; nt++)
      vf[nt] = *(const bf16x8*)(&Vt[nt * 16 + l16][kt * 32 + quad * 8]);
    #pragma unroll
    for (int mt = 0; mt < 4; mt++)
      #pragma unroll
      for (int nt = 0; nt < 2; nt++)
        O[mt][nt] = __builtin_amdgcn_mfma_f32_16x16x32_bf16(pf[mt], vf[nt], O[mt][nt], 0, 0, 0);
  }

  __bf16* ob = o + (long)win * NTOK * DIM_ + h * 32;
  #pragma unroll
  for (int mt = 0; mt < 4; mt++)
    #pragma unroll
    for (int r = 0; r < 4; r++) {
      int q = mt * 16 + quad * 4 + r;
      if (q < NTOK) {
        #pragma unroll
        for (int nt = 0; nt < 2; nt++)
          ob[(long)q * DIM_ + nt * 16 + l16] = (__bf16)O[mt][nt][r];
      }
    }
}

// ---------------------------------------------------------------------------
// LDS-free direct-load bf16 MFMA GEMM. C(MxN) = A(MxK) @ Bt(NxK)^T.
// Tile 128 x TN, 4 waves (2x2). A/B fragments loaded straight from global in
// MFMA layout: lane (quad,l16) reads row base+l16, 16B at k0+quad*8. Each
// 64B line is fully consumed by one quad-group -> no bandwidth waste; B is
// L2-resident (<=1.2MB). No barriers in the K-loop -> waves pipeline freely.
// MODE 0: qkv   -> bf16 out = acc + bias
// MODE 1: proj  -> window-reverse scatter: X1 = x + acc + bias (valid pixels)
// MODE 2: fc1   -> bf16 out = gelu_fast(acc + bias)
// MODE 3: fc2   -> f32 out = acc + bias + res
// ---------------------------------------------------------------------------
template <int MODE, int TN, int KK>
__global__ void __launch_bounds__(256)
gemm_direct(const __bf16* __restrict__ A, const __bf16* __restrict__ Bt,
            const float* __restrict__ bias, int N,
            float* __restrict__ outf, __bf16* __restrict__ outb,
            const float* __restrict__ res) {
  constexpr int NT = TN / 32;                 // acc col-tiles per wave
  int tid = threadIdx.x, lane = tid & 63, wid = tid >> 6;
  int wm = wid >> 1, wn = wid & 1;
  int quad = lane >> 4, l16 = lane & 15;
  long tileM = (long)blockIdx.x * 128;
  long tileN = (long)blockIdx.y * TN;

  f32x4 acc[4][NT];
  #pragma unroll
  for (int i = 0; i < 4; i++)
    #pragma unroll
    for (int j = 0; j < NT; j++) acc[i][j] = (f32x4){0.f, 0.f, 0.f, 0.f};

  const __bf16* aBase = A  + (tileM + wm * 64 + l16) * (long)KK + quad * 8;
  const __bf16* bBase = Bt + (tileN + wn * (TN / 2) + l16) * (long)KK + quad * 8;

  #pragma unroll 2
  for (int k0 = 0; k0 < KK; k0 += 32) {
    bf16x8 af[4], bfr[NT];
    #pragma unroll
    for (int mt = 0; mt < 4; mt++)
      af[mt] = *(const bf16x8*)(aBase + (long)mt * 16 * KK + k0);
    #pragma unroll
    for (int nt = 0; nt < NT; nt++)
      bfr[nt] = *(const bf16x8*)(bBase + (long)nt * 16 * KK + k0);
    #pragma unroll
    for (int mt = 0; mt < 4; mt++)
      #pragma unroll
      for (int nt = 0; nt < NT; nt++)
        acc[mt][nt] = __builtin_amdgcn_mfma_f32_16x16x32_bf16(af[mt], bfr[nt], acc[mt][nt], 0, 0, 0);
  }

  float bcol[NT];
  #pragma unroll
  for (int nt = 0; nt < NT; nt++) bcol[nt] = bias[tileN + wn * (TN / 2) + nt * 16 + l16];

  #pragma unroll
  for (int mt = 0; mt < 4; mt++) {
    #pragma unroll
    for (int r = 0; r < 4; r++) {
      long row = tileM + wm * 64 + mt * 16 + quad * 4 + r;
      if (MODE == 0) {
        __bf16* orow = outb + row * (long)N;
        #pragma unroll
        for (int nt = 0; nt < NT; nt++)
          orow[tileN + wn * (TN / 2) + nt * 16 + l16] = (__bf16)(acc[mt][nt][r] + bcol[nt]);
      } else if (MODE == 1) {
        if (row < MREAL) {
          int r32 = (int)row;
          int win = r32 / NTOK, t = r32 % NTOK;
          int rem = win % 100;
          int pr = (rem / 10) * 7 + t / 7;
          int pc = (rem % 10) * 7 + t % 7;
          if (pr < 64 && pc < 64) {
            long po = ((long)(win / 100) * 4096 + pr * 64 + pc) * DIM_;
            #pragma unroll
            for (int nt = 0; nt < NT; nt++) {
              long col = tileN + wn * (TN / 2) + nt * 16 + l16;
              outf[po + col] = res[po + col] + acc[mt][nt][r] + bcol[nt];
            }
          }
        }
      } else if (MODE == 2) {
        __bf16* orow = outb + row * (long)N;
        #pragma unroll
        for (int nt = 0; nt < NT; nt++) {
          float v = acc[mt][nt][r] + bcol[nt];
          orow[tileN + wn * (TN / 2) + nt * 16 + l16] = (__bf16)gelu_fast(v);
        }
      } else {
        float* orow = outf + row * (long)N;
        const float* rrow = res + row * (long)N;
        #pragma unroll
        for (int nt = 0; nt < NT; nt++) {
          long col = tileN + wn * (TN / 2) + nt * 16 + l16;
          orow[col] = acc[mt][nt][r] + bcol[nt] + rrow[col];
        }
      }
    }
  }
}

// ---------------------------------------------------------------------------
extern "C" void kernel_launch(void* const* d_in, const int* in_sizes, int n_in,
                              void* d_out, int out_size, void* d_ws, size_t ws_size,
                              hipStream_t stream) {
  const float* x       = (const float*)d_in[0];
  const float* ln1_g   = (const float*)d_in[1];
  const float* ln1_b   = (const float*)d_in[2];
  const float* qkv_w   = (const float*)d_in[3];
  const float* qkv_b   = (const float*)d_in[4];
  const float* proj_w  = (const float*)d_in[5];
  const float* proj_b  = (const float*)d_in[6];
  const float* attn_b  = (const float*)d_in[7];
  const float* conv_w  = (const float*)d_in[8];
  const float* bn_g    = (const float*)d_in[9];
  const float* bn_b    = (const float*)d_in[10];
  const float* bn_mean = (const float*)d_in[11];
  const float* bn_var  = (const float*)d_in[12];
  const float* ln2_g   = (const float*)d_in[13];
  const float* ln2_b   = (const float*)d_in[14];
  const float* fc1_w   = (const float*)d_in[15];
  const float* fc1_b   = (const float*)d_in[16];
  const float* fc2_w   = (const float*)d_in[17];
  const float* fc2_b   = (const float*)d_in[18];

  // workspace layout (aliasing; ~130 MB total):
  char* p = (char*)d_ws;
  __bf16* WQKV = (__bf16*)p;  p += 884736;     // 1152x384
  __bf16* WPROJ = (__bf16*)p; p += 294912;     // 384x384
  __bf16* WFC1 = (__bf16*)p;  p += 1179648;    // 1536x384
  __bf16* WFC2 = (__bf16*)p;  p += 1179648;    // 384x1536
  float*  WCONV = (float*)p;  p += 13824;      // 9x384
  char* region = p;           p += 75694080;
  float* X1 = (float*)p;      p += 25165824;
  float* X2 = (float*)p;      p += 25165824;
  __bf16* XN   = (__bf16*)region;                 // 19712x384 (dead after QKV gemm)
  __bf16* QKVB = (__bf16*)(region + 15138816);    // 19712x1152
  __bf16* OBUF = (__bf16*)(region + 60555264);    // 19712x384
  __bf16* XLN2 = (__bf16*)region;                 // 16384x384  (aliases XN, dead)
  __bf16* H1   = (__bf16*)(region + 15138816);    // 16384x1536 (aliases QKVB+OBUF, dead)
  float*  BM   = X1;                              // 12x64x64 bias table; X1 not yet live
  float* OUT = (float*)d_out;

  prep_all<<<B_TOTAL, 256, 0, stream>>>(x, ln1_g, ln1_b, XN,
                                        qkv_w, WQKV, proj_w, WPROJ,
                                        fc1_w, WFC1, fc2_w, WFC2,
                                        conv_w, WCONV, attn_b, BM);

  gemm_direct<0, 128, DIM_><<<dim3(MPAD / 128, QKVD / 128), 256, 0, stream>>>(
      XN, WQKV, qkv_b, QKVD, nullptr, QKVB, nullptr);

  attn_mfma<<<NWIN * 12, 64, 0, stream>>>(QKVB, BM, OBUF);

  gemm_direct<1, 64, DIM_><<<dim3(MPAD / 128, DIM_ / 64), 256, 0, stream>>>(
      OBUF, WPROJ, proj_b, DIM_, X1, nullptr, x);

  conv_bn_ln2<<<TOKENS / 4, 384, 0, stream>>>(X1, WCONV, bn_g, bn_b, bn_mean, bn_var,
                                              ln2_g, ln2_b, X2, XLN2);

  gemm_direct<2, 128, DIM_><<<dim3(TOKENS / 128, HIDD / 128), 256, 0, stream>>>(
      XLN2, WFC1, fc1_b, HIDD, nullptr, H1, nullptr);

  gemm_direct<3, 64, HIDD><<<dim3(TOKENS / 128, DIM_ / 64), 256, 0, stream>>>(
      H1, WFC2, fc2_b, DIM_, OUT, nullptr, X2);
}

// Round 8
// 329.722 us; speedup vs baseline: 1.3863x; 1.3863x over previous
//
#include <hip/hip_runtime.h>
#include <cstdint>

// ---------------------------------------------------------------------------
// TinyViT block on gfx950. Round 8: revert to round-5 BK=32 LDS K-loop
// (round-7 direct-load was latency-bound: MfmaUtil 7%), but with SWAPPED
// operand roles: A = weights (features x K), B = activations (tokens x K).
// D[row=feature][col=token] => in-lane f32x4 = 4 consecutive features of one
// token => fully vectorized epilogues (f32x4/bf16x4 stores, f32x4 bias/res).
// Keeps round-6 fused prep kernel.
// ---------------------------------------------------------------------------

typedef __bf16 bf16x8 __attribute__((ext_vector_type(8)));
typedef __bf16 bf16x4 __attribute__((ext_vector_type(4)));
typedef float  f32x4  __attribute__((ext_vector_type(4)));

#define DIM_    384
#define QKVD    1152
#define HIDD    1536
#define NTOK    49
#define NWIN    400
#define MPAD    19712     /* 154*128 */
#define MREAL   19600
#define TOKENS  16384     /* 4*4096 */
#define SCALE_  0.17677669529663689f
#define EPS_    1e-5f

// prep job block ranges (256 threads each)
#define B_LN1   9856      /* 19712 tokens, 2 per block        */
#define B_QKV   1728      /* 442368 elems                     */
#define B_PROJ  576       /* 147456                           */
#define B_FC1   2304      /* 589824                           */
#define B_FC2   2304      /* 589824                           */
#define B_CONV  14        /* 3456                             */
#define B_BIAS  192       /* 49152                            */
#define B_TOTAL (B_LN1 + B_QKV + B_PROJ + B_FC1 + B_FC2 + B_CONV + B_BIAS)

__device__ __forceinline__ void gload_lds16(const void* g, void* l) {
  __builtin_amdgcn_global_load_lds(
      (__attribute__((address_space(1))) void*)g,
      (__attribute__((address_space(3))) void*)l, 16, 0, 0);
}

// tanh-form GELU via sigmoid + fast rcp
__device__ __forceinline__ float gelu_fast(float v) {
  float t2 = v * (1.5957691216057308f + 0.07135481627f * v * v);
  return v * __builtin_amdgcn_rcpf(1.f + __expf(-t2));
}

// ---------------------------------------------------------------------------
// Fused prep: LN1+window partition, 4 weight transposes, conv-w transpose,
// attention bias table. One kernel, block-range dispatch, 256 threads.
// ---------------------------------------------------------------------------
__global__ __launch_bounds__(256) void prep_all(
    const float* __restrict__ x, const float* __restrict__ ln1_g,
    const float* __restrict__ ln1_b, __bf16* __restrict__ xn,
    const float* __restrict__ qkv_w,  __bf16* __restrict__ wqkv,
    const float* __restrict__ proj_w, __bf16* __restrict__ wproj,
    const float* __restrict__ fc1_w,  __bf16* __restrict__ wfc1,
    const float* __restrict__ fc2_w,  __bf16* __restrict__ wfc2,
    const float* __restrict__ conv_w, float* __restrict__ wconv,
    const float* __restrict__ attn_b, float* __restrict__ bm) {
  int b = blockIdx.x;
  int tid = threadIdx.x;

  if (b < B_LN1) {
    // ---- LN1 + window partition: 2 tokens per block, no early returns ----
    int sub = tid >> 7, tl = tid & 127;
    int t = b * 2 + sub;                       // 0..19711
    __bf16* orow = xn + (long)t * DIM_;
    int kind;                                  // 0=valid 1=bet-pad 2=zero-pad
    int bb = 0, r = 0, c = 0;
    if (t >= MREAL) kind = 2;
    else {
      int win = t / NTOK, tt = t % NTOK;
      bb = win / 100;
      int rem = win % 100;
      r = (rem / 10) * 7 + tt / 7;
      c = (rem % 10) * 7 + tt % 7;
      kind = (r >= 64 || c >= 64) ? 1 : 0;
    }
    float v0 = 0.f, v1 = 0.f, v2 = 0.f;
    if (kind == 0) {
      const float* xr = x + ((long)bb * 4096 + r * 64 + c) * DIM_;
      v0 = xr[tl]; v1 = xr[tl + 128]; v2 = xr[tl + 256];
    }
    float s = v0 + v1 + v2, s2 = v0 * v0 + v1 * v1 + v2 * v2;
    for (int off = 32; off; off >>= 1) { s += __shfl_down(s, off); s2 += __shfl_down(s2, off); }
    __shared__ float red[2][4];
    if ((tl & 63) == 0) { red[sub][tl >> 6] = s; red[sub][2 + (tl >> 6)] = s2; }
    __syncthreads();
    float S = red[sub][0] + red[sub][1], S2 = red[sub][2] + red[sub][3];
    float m  = S * (1.f / DIM_);
    float rs = rsqrtf(S2 * (1.f / DIM_) - m * m + EPS_);
    if (kind == 0) {
      orow[tl]       = (__bf16)((v0 - m) * rs * ln1_g[tl]       + ln1_b[tl]);
      orow[tl + 128] = (__bf16)((v1 - m) * rs * ln1_g[tl + 128] + ln1_b[tl + 128]);
      orow[tl + 256] = (__bf16)((v2 - m) * rs * ln1_g[tl + 256] + ln1_b[tl + 256]);
    } else if (kind == 1) {
      orow[tl]       = (__bf16)ln1_b[tl];
      orow[tl + 128] = (__bf16)ln1_b[tl + 128];
      orow[tl + 256] = (__bf16)ln1_b[tl + 256];
    } else {
      orow[tl] = (__bf16)0.f; orow[tl + 128] = (__bf16)0.f; orow[tl + 256] = (__bf16)0.f;
    }
    return;
  }
  b -= B_LN1;
  if (b < B_QKV) {               // qkv_w (384x1152) -> wqkv (1152x384)
    int id = b * 256 + tid;      // < 442368 exactly
    int k = id % DIM_; int n = id / DIM_;
    wqkv[id] = (__bf16)qkv_w[(long)k * QKVD + n];
    return;
  }
  b -= B_QKV;
  if (b < B_PROJ) {              // proj_w (384x384) -> wproj (384x384)^T
    int id = b * 256 + tid;
    int k = id % DIM_; int n = id / DIM_;
    wproj[id] = (__bf16)proj_w[(long)k * DIM_ + n];
    return;
  }
  b -= B_PROJ;
  if (b < B_FC1) {               // fc1_w (384x1536) -> wfc1 (1536x384)
    int id = b * 256 + tid;
    int k = id % DIM_; int n = id / DIM_;
    wfc1[id] = (__bf16)fc1_w[(long)k * HIDD + n];
    return;
  }
  b -= B_FC1;
  if (b < B_FC2) {               // fc2_w (1536x384) -> wfc2 (384x1536)
    int id = b * 256 + tid;
    int k = id % HIDD; int n = id / HIDD;
    wfc2[id] = (__bf16)fc2_w[(long)k * DIM_ + n];
    return;
  }
  b -= B_FC2;
  if (b < B_CONV) {              // conv_w [384][9] -> wconv [9][384]
    int id = b * 256 + tid;
    if (id < 3456) {
      int ch = id / 9, k = id % 9;
      wconv[k * DIM_ + ch] = conv_w[id];
    }
    return;
  }
  b -= B_CONV;
  {                              // bias table bm[12][64][64]
    int id = b * 256 + tid;      // < 49152
    int h = id >> 12, q = (id >> 6) & 63, kk = id & 63;
    float v;
    if (kk >= NTOK)      v = -1e30f;
    else if (q >= NTOK)  v = 0.f;
    else {
      int idx = abs(q / 7 - kk / 7) * 7 + abs(q % 7 - kk % 7);
      v = attn_b[h * NTOK + idx];
    }
    bm[id] = v;
  }
}

// ---------------------------------------------------------------------------
// Fused depthwise 3x3 conv + BN + LN2. Block = 4 pixels x 96 lanes (384 thr).
// ---------------------------------------------------------------------------
__global__ __launch_bounds__(384) void conv_bn_ln2(
    const float* __restrict__ x1, const float* __restrict__ wT,
    const float* __restrict__ bng, const float* __restrict__ bnb,
    const float* __restrict__ mean, const float* __restrict__ var,
    const float* __restrict__ g2, const float* __restrict__ b2,
    float* __restrict__ x2, __bf16* __restrict__ xln2) {
  int tid = threadIdx.x;
  int p = tid / 96, g = tid % 96;
  int pix = blockIdx.x * 4 + p;            // 0..16383
  int bb = pix >> 12, rc = pix & 4095;
  int r = rc >> 6, c = rc & 63;
  int ch = g << 2;

  f32x4 acc = (f32x4){0.f, 0.f, 0.f, 0.f};
  #pragma unroll
  for (int dr = -1; dr <= 1; dr++) {
    int rr = r + dr;
    if (rr < 0 || rr >= 64) continue;
    #pragma unroll
    for (int dc = -1; dc <= 1; dc++) {
      int cc = c + dc;
      if (cc < 0 || cc >= 64) continue;
      f32x4 xv = *(const f32x4*)(x1 + ((long)bb * 4096 + rr * 64 + cc) * DIM_ + ch);
      f32x4 wv = *(const f32x4*)(wT + ((dr + 1) * 3 + (dc + 1)) * DIM_ + ch);
      acc += xv * wv;
    }
  }

  f32x4 gv = *(const f32x4*)(bng + ch);
  f32x4 vv = *(const f32x4*)(var + ch);
  f32x4 mv = *(const f32x4*)(mean + ch);
  f32x4 bv = *(const f32x4*)(bnb + ch);
  f32x4 y;
  #pragma unroll
  for (int j = 0; j < 4; j++) {
    float sc = gv[j] * rsqrtf(vv[j] + EPS_);
    y[j] = acc[j] * sc + (bv[j] - mv[j] * sc);
  }
  *(f32x4*)(x2 + (long)pix * DIM_ + ch) = y;

  __shared__ float pS[4][96], pS2[4][96], mS[4], rS[4];
  pS[p][g]  = y[0] + y[1] + y[2] + y[3];
  pS2[p][g] = y[0] * y[0] + y[1] * y[1] + y[2] * y[2] + y[3] * y[3];
  __syncthreads();
  if (g < 32) {
    float a  = pS[p][g]  + pS[p][g + 32]  + pS[p][g + 64];
    float a2 = pS2[p][g] + pS2[p][g + 32] + pS2[p][g + 64];
    #pragma unroll
    for (int off = 1; off < 32; off <<= 1) {
      a  += __shfl_xor(a, off);
      a2 += __shfl_xor(a2, off);
    }
    if (g == 0) {
      float m = a * (1.f / DIM_);
      mS[p] = m;
      rS[p] = rsqrtf(a2 * (1.f / DIM_) - m * m + EPS_);
    }
  }
  __syncthreads();
  float m = mS[p], rs = rS[p];
  f32x4 gg = *(const f32x4*)(g2 + ch);
  f32x4 b2v = *(const f32x4*)(b2 + ch);
  bf16x4 ov;
  #pragma unroll
  for (int j = 0; j < 4; j++) ov[j] = (__bf16)((y[j] - m) * rs * gg[j] + b2v[j]);
  *(bf16x4*)(xln2 + (long)pix * DIM_ + ch) = ov;
}

// ---------------------------------------------------------------------------
// MFMA attention: one 64-thread block per (window, head). 4800 blocks.
// ---------------------------------------------------------------------------
__global__ __launch_bounds__(64) void attn_mfma(const __bf16* __restrict__ qkv,
                                                const float* __restrict__ bm,
                                                __bf16* __restrict__ o) {
  int blk = blockIdx.x;
  int win = blk / 12, h = blk % 12;
  int lane = threadIdx.x;
  int quad = lane >> 4, l16 = lane & 15;

  __shared__ __align__(16) __bf16 Vt[32][72];   // Vt[d][kk]
  __shared__ __align__(16) __bf16 P[64][72];    // P[q][kk]

  const __bf16* base = qkv + (long)win * NTOK * QKVD + h * 96;

  bf16x8 qf[4], kf[4];
  #pragma unroll
  for (int t = 0; t < 4; t++) {
    const __bf16* rp = base + (long)(t * 16 + l16) * QKVD + quad * 8;
    qf[t] = *(const bf16x8*)(rp);
    kf[t] = *(const bf16x8*)(rp + 32);
  }
  {
    const __bf16* vp = base + (long)lane * QKVD + 64;
    bf16x8 vv[4];
    #pragma unroll
    for (int i = 0; i < 4; i++) vv[i] = *(const bf16x8*)(vp + i * 8);
    #pragma unroll
    for (int i = 0; i < 4; i++)
      #pragma unroll
      for (int j = 0; j < 8; j++) Vt[i * 8 + j][lane] = vv[i][j];
  }

  f32x4 S[4][4];
  #pragma unroll
  for (int i = 0; i < 4; i++)
    #pragma unroll
    for (int j = 0; j < 4; j++) S[i][j] = (f32x4){0.f, 0.f, 0.f, 0.f};
  #pragma unroll
  for (int mt = 0; mt < 4; mt++)
    #pragma unroll
    for (int nt = 0; nt < 4; nt++)
      S[mt][nt] = __builtin_amdgcn_mfma_f32_16x16x32_bf16(qf[mt], kf[nt], S[mt][nt], 0, 0, 0);

  const float* bmh = bm + h * 4096;
  #pragma unroll
  for (int mt = 0; mt < 4; mt++)
    #pragma unroll
    for (int r = 0; r < 4; r++) {
      int q = mt * 16 + quad * 4 + r;
      #pragma unroll
      for (int nt = 0; nt < 4; nt++)
        S[mt][nt][r] = S[mt][nt][r] * SCALE_ + bmh[q * 64 + nt * 16 + l16];
    }

  #pragma unroll
  for (int mt = 0; mt < 4; mt++)
    #pragma unroll
    for (int r = 0; r < 4; r++) {
      float mx = fmaxf(fmaxf(S[mt][0][r], S[mt][1][r]), fmaxf(S[mt][2][r], S[mt][3][r]));
      #pragma unroll
      for (int off = 1; off < 16; off <<= 1) mx = fmaxf(mx, __shfl_xor(mx, off));
      float sum = 0.f;
      #pragma unroll
      for (int nt = 0; nt < 4; nt++) {
        float e = __expf(S[mt][nt][r] - mx);
        S[mt][nt][r] = e;
        sum += e;
      }
      #pragma unroll
      for (int off = 1; off < 16; off <<= 1) sum += __shfl_xor(sum, off);
      float inv = 1.f / sum;
      #pragma unroll
      for (int nt = 0; nt < 4; nt++) S[mt][nt][r] *= inv;
    }

  #pragma unroll
  for (int mt = 0; mt < 4; mt++)
    #pragma unroll
    for (int r = 0; r < 4; r++) {
      int q = mt * 16 + quad * 4 + r;
      #pragma unroll
      for (int nt = 0; nt < 4; nt++)
        P[q][nt * 16 + l16] = (__bf16)S[mt][nt][r];
    }
  __syncthreads();

  f32x4 O[4][2];
  #pragma unroll
  for (int i = 0; i < 4; i++)
    #pragma unroll
    for (int j = 0; j < 2; j++) O[i][j] = (f32x4){0.f, 0.f, 0.f, 0.f};
  #pragma unroll
  for (int kt = 0; kt < 2; kt++) {
    bf16x8 pf[4], vf[2];
    #pragma unroll
    for (int mt = 0; mt < 4; mt++)
      pf[mt] = *(const bf16x8*)(&P[mt * 16 + l16][kt * 32 + quad * 8]);
    #pragma unroll
    for (int nt = 0; nt < 2; nt++)
      vf[nt] = *(const bf16x8*)(&Vt[nt * 16 + l16][kt * 32 + quad * 8]);
    #pragma unroll
    for (int mt = 0; mt < 4; mt++)
      #pragma unroll
      for (int nt = 0; nt < 2; nt++)
        O[mt][nt] = __builtin_amdgcn_mfma_f32_16x16x32_bf16(pf[mt], vf[nt], O[mt][nt], 0, 0, 0);
  }

  __bf16* ob = o + (long)win * NTOK * DIM_ + h * 32;
  #pragma unroll
  for (int mt = 0; mt < 4; mt++)
    #pragma unroll
    for (int r = 0; r < 4; r++) {
      int q = mt * 16 + quad * 4 + r;
      if (q < NTOK) {
        #pragma unroll
        for (int nt = 0; nt < 2; nt++)
          ob[(long)q * DIM_ + nt * 16 + l16] = (__bf16)O[mt][nt][r];
      }
    }
}

// ---------------------------------------------------------------------------
// Swapped-operand bf16 MFMA GEMM.
//   W   : [MF x K]  weights, K-contiguous (MF = out-features, mult of 128)
//   Act : [NTOKS x K] activations, K-contiguous
//   Out[token][feature] = sum_k Act[token][k] * W[feature][k] (+bias etc.)
// Tile: 128 features x TN tokens; 4 waves 2x2; BK=32 LDS staging via
// global_load_lds(16B) (round-5 verified layout). D[row=feature][col=token]
// => in-lane f32x4 = 4 consecutive features of one token => vector epilogue.
// MODE 0: qkv  -> bf16 Out = acc + bias
// MODE 1: proj -> window-reverse scatter: X1 = x + acc + bias (valid tokens)
// MODE 2: fc1  -> bf16 Out = gelu_fast(acc + bias)
// MODE 3: fc2  -> f32 Out = acc + bias + res
// ---------------------------------------------------------------------------
template <int MODE, int TN>
__global__ void __launch_bounds__(256)
gemm_w(const __bf16* __restrict__ W, const __bf16* __restrict__ Act,
       const float* __restrict__ bias, int K, int ldOut,
       float* __restrict__ outf, __bf16* __restrict__ outb,
       const float* __restrict__ res) {
  constexpr int NT = TN / 32;                 // token 16-tiles per wave
  __shared__ __align__(16) __bf16 sA[128 * 32];
  __shared__ __align__(16) __bf16 sB[TN * 32];
  int tid = threadIdx.x, lane = tid & 63, wid = tid >> 6;
  int wm = wid >> 1, wn = wid & 1;
  int quad = lane >> 4, l16 = lane & 15;
  long tileM = (long)blockIdx.x * 128;        // feature dim
  long tileN = (long)blockIdx.y * TN;         // token dim

  f32x4 acc[4][NT];
  #pragma unroll
  for (int i = 0; i < 4; i++)
    #pragma unroll
    for (int j = 0; j < NT; j++) acc[i][j] = (f32x4){0.f, 0.f, 0.f, 0.f};

  int rr = wid * 16 + (lane >> 2);
  const __bf16* gA = W   + (tileM + rr) * (long)K + ((lane & 3) << 3);
  const __bf16* gB = Act + (tileN + rr) * (long)K + ((lane & 3) << 3);
  const long rowskip = 64 * (long)K;

  for (int k0 = 0; k0 < K; k0 += 32) {
    gload_lds16(gA + k0,           sA + (wid << 9));
    gload_lds16(gA + k0 + rowskip, sA + ((wid + 4) << 9));
    gload_lds16(gB + k0,           sB + (wid << 9));
    if (TN == 128)
      gload_lds16(gB + k0 + rowskip, sB + ((wid + 4) << 9));
    __syncthreads();
    bf16x8 af[4], bfr[NT];
    #pragma unroll
    for (int mt = 0; mt < 4; mt++)
      af[mt] = *(const bf16x8*)(sA + ((wm * 64 + mt * 16 + l16) << 5) + (quad << 3));
    #pragma unroll
    for (int nt = 0; nt < NT; nt++)
      bfr[nt] = *(const bf16x8*)(sB + ((wn * (TN / 2) + nt * 16 + l16) << 5) + (quad << 3));
    #pragma unroll
    for (int mt = 0; mt < 4; mt++)
      #pragma unroll
      for (int nt = 0; nt < NT; nt++)
        acc[mt][nt] = __builtin_amdgcn_mfma_f32_16x16x32_bf16(af[mt], bfr[nt], acc[mt][nt], 0, 0, 0);
    __syncthreads();
  }

  // ---- epilogue: lane holds, per (mt,nt), features featW+mt*16+quad*4+{0..3}
  //      of token tileN + wn*(TN/2) + nt*16 + l16. All accesses vectorized. ----
  int featW = (int)tileM + wm * 64 + quad * 4;
  f32x4 bv[4];
  #pragma unroll
  for (int mt = 0; mt < 4; mt++)
    bv[mt] = *(const f32x4*)(bias + featW + mt * 16);

  #pragma unroll
  for (int nt = 0; nt < NT; nt++) {
    int tok = (int)tileN + wn * (TN / 2) + nt * 16 + l16;
    if (MODE == 0 || MODE == 2) {
      __bf16* obase = outb + (long)tok * ldOut + featW;
      #pragma unroll
      for (int mt = 0; mt < 4; mt++) {
        f32x4 v = acc[mt][nt] + bv[mt];
        bf16x4 ov;
        #pragma unroll
        for (int j = 0; j < 4; j++)
          ov[j] = (MODE == 2) ? (__bf16)gelu_fast(v[j]) : (__bf16)v[j];
        *(bf16x4*)(obase + mt * 16) = ov;
      }
    } else if (MODE == 1) {
      if (tok < MREAL) {
        int win = tok / NTOK, tt = tok % NTOK;
        int rem = win % 100;
        int pr = (rem / 10) * 7 + tt / 7;
        int pc = (rem % 10) * 7 + tt % 7;
        if (pr < 64 && pc < 64) {
          long po = ((long)(win / 100) * 4096 + pr * 64 + pc) * DIM_ + featW;
          #pragma unroll
          for (int mt = 0; mt < 4; mt++) {
            f32x4 rv = *(const f32x4*)(res + po + mt * 16);
            *(f32x4*)(outf + po + mt * 16) = rv + acc[mt][nt] + bv[mt];
          }
        }
      }
    } else {   // MODE 3
      float* obase = outf + (long)tok * ldOut + featW;
      const float* rbase = res + (long)tok * ldOut + featW;
      #pragma unroll
      for (int mt = 0; mt < 4; mt++) {
        f32x4 rv = *(const f32x4*)(rbase + mt * 16);
        *(f32x4*)(obase + mt * 16) = rv + acc[mt][nt] + bv[mt];
      }
    }
  }
}

// ---------------------------------------------------------------------------
extern "C" void kernel_launch(void* const* d_in, const int* in_sizes, int n_in,
                              void* d_out, int out_size, void* d_ws, size_t ws_size,
                              hipStream_t stream) {
  const float* x       = (const float*)d_in[0];
  const float* ln1_g   = (const float*)d_in[1];
  const float* ln1_b   = (const float*)d_in[2];
  const float* qkv_w   = (const float*)d_in[3];
  const float* qkv_b   = (const float*)d_in[4];
  const float* proj_w  = (const float*)d_in[5];
  const float* proj_b  = (const float*)d_in[6];
  const float* attn_b  = (const float*)d_in[7];
  const float* conv_w  = (const float*)d_in[8];
  const float* bn_g    = (const float*)d_in[9];
  const float* bn_b    = (const float*)d_in[10];
  const float* bn_mean = (const float*)d_in[11];
  const float* bn_var  = (const float*)d_in[12];
  const float* ln2_g   = (const float*)d_in[13];
  const float* ln2_b   = (const float*)d_in[14];
  const float* fc1_w   = (const float*)d_in[15];
  const float* fc1_b   = (const float*)d_in[16];
  const float* fc2_w   = (const float*)d_in[17];
  const float* fc2_b   = (const float*)d_in[18];

  // workspace layout (aliasing; ~130 MB total):
  char* p = (char*)d_ws;
  __bf16* WQKV = (__bf16*)p;  p += 884736;     // 1152x384
  __bf16* WPROJ = (__bf16*)p; p += 294912;     // 384x384
  __bf16* WFC1 = (__bf16*)p;  p += 1179648;    // 1536x384
  __bf16* WFC2 = (__bf16*)p;  p += 1179648;    // 384x1536
  float*  WCONV = (float*)p;  p += 13824;      // 9x384
  char* region = p;           p += 75694080;
  float* X1 = (float*)p;      p += 25165824;
  float* X2 = (float*)p;      p += 25165824;
  __bf16* XN   = (__bf16*)region;                 // 19712x384 (dead after QKV gemm)
  __bf16* QKVB = (__bf16*)(region + 15138816);    // 19712x1152
  __bf16* OBUF = (__bf16*)(region + 60555264);    // 19712x384
  __bf16* XLN2 = (__bf16*)region;                 // 16384x384  (aliases XN, dead)
  __bf16* H1   = (__bf16*)(region + 15138816);    // 16384x1536 (aliases QKVB+OBUF, dead)
  float*  BM   = X1;                              // 12x64x64 bias table; X1 not yet live
  float* OUT = (float*)d_out;

  prep_all<<<B_TOTAL, 256, 0, stream>>>(x, ln1_g, ln1_b, XN,
                                        qkv_w, WQKV, proj_w, WPROJ,
                                        fc1_w, WFC1, fc2_w, WFC2,
                                        conv_w, WCONV, attn_b, BM);

  // qkv: 1152 features x 19712 tokens, K=384
  gemm_w<0, 128><<<dim3(QKVD / 128, MPAD / 128), 256, 0, stream>>>(
      WQKV, XN, qkv_b, DIM_, QKVD, nullptr, QKVB, nullptr);

  attn_mfma<<<NWIN * 12, 64, 0, stream>>>(QKVB, BM, OBUF);

  // proj: 384 features x 19712 tokens, K=384, window-reverse scatter + residual
  gemm_w<1, 64><<<dim3(DIM_ / 128, MPAD / 64), 256, 0, stream>>>(
      WPROJ, OBUF, proj_b, DIM_, DIM_, X1, nullptr, x);

  conv_bn_ln2<<<TOKENS / 4, 384, 0, stream>>>(X1, WCONV, bn_g, bn_b, bn_mean, bn_var,
                                              ln2_g, ln2_b, X2, XLN2);

  // fc1: 1536 features x 16384 tokens, K=384, gelu
  gemm_w<2, 64><<<dim3(HIDD / 128, TOKENS / 64), 256, 0, stream>>>(
      WFC1, XLN2, fc1_b, DIM_, HIDD, nullptr, H1, nullptr);

  // fc2: 384 features x 16384 tokens, K=1536, + residual -> OUT
  gemm_w<3, 64><<<dim3(DIM_ / 128, TOKENS / 64), 256, 0, stream>>>(
      WFC2, H1, fc2_b, HIDD, DIM_, OUT, nullptr, X2);
}

// Round 9
// 287.236 us; speedup vs baseline: 1.5913x; 1.1479x over previous
//
#include <hip/hip_runtime.h>
#include <cstdint>

// ---------------------------------------------------------------------------
// TinyViT block on gfx950. Round 9: revert GEMM to round-5 structure (best
// measured: BK=32 single buffer, activations-as-A). Structural change:
// token-compact pipeline. All pad-window tokens share one LN1 row (ln1_b),
// so qkv runs on 16384 real tokens + 1 shared pad row (M=16512, was 19712).
// Attention gathers rows by window->token decode and scatters O in token
// order (window-reverse fused into attn store). Proj becomes a plain
// M=16384 GEMM with the same res+bias epilogue as fc2.
// ---------------------------------------------------------------------------

typedef __bf16 bf16x8 __attribute__((ext_vector_type(8)));
typedef __bf16 bf16x4 __attribute__((ext_vector_type(4)));
typedef float  f32x4  __attribute__((ext_vector_type(4)));

#define DIM_    384
#define QKVD    1152
#define HIDD    1536
#define NTOK    49
#define NWIN    400
#define TOKENS  16384     /* 4*4096 real tokens */
#define PADROW  16384     /* shared pad-token row index */
#define MQKV    16512     /* 129*128: 16384 tokens + pad row + slack */
#define SCALE_  0.17677669529663689f
#define EPS_    1e-5f

// prep job block ranges (256 threads each)
#define B_LN1   8192      /* 16384 tokens, 2 per block */
#define B_PADR  1         /* shared pad row = ln1_b    */
#define B_QKV   1728      /* 442368 elems              */
#define B_PROJ  576       /* 147456                    */
#define B_FC1   2304      /* 589824                    */
#define B_FC2   2304      /* 589824                    */
#define B_CONV  14        /* 3456                      */
#define B_BIAS  192       /* 49152                     */
#define B_TOTAL (B_LN1 + B_PADR + B_QKV + B_PROJ + B_FC1 + B_FC2 + B_CONV + B_BIAS)

__device__ __forceinline__ void gload_lds16(const void* g, void* l) {
  __builtin_amdgcn_global_load_lds(
      (__attribute__((address_space(1))) void*)g,
      (__attribute__((address_space(3))) void*)l, 16, 0, 0);
}

// tanh-form GELU via sigmoid + fast rcp
__device__ __forceinline__ float gelu_fast(float v) {
  float t2 = v * (1.5957691216057308f + 0.07135481627f * v * v);
  return v * __builtin_amdgcn_rcpf(1.f + __expf(-t2));
}

// ---------------------------------------------------------------------------
// Fused prep: LN1 (plain token rows), shared pad row, 4 weight transposes,
// conv-w transpose, attention bias table.
// ---------------------------------------------------------------------------
__global__ __launch_bounds__(256) void prep_all(
    const float* __restrict__ x, const float* __restrict__ ln1_g,
    const float* __restrict__ ln1_b, __bf16* __restrict__ xn,
    const float* __restrict__ qkv_w,  __bf16* __restrict__ wqkv,
    const float* __restrict__ proj_w, __bf16* __restrict__ wproj,
    const float* __restrict__ fc1_w,  __bf16* __restrict__ wfc1,
    const float* __restrict__ fc2_w,  __bf16* __restrict__ wfc2,
    const float* __restrict__ conv_w, float* __restrict__ wconv,
    const float* __restrict__ attn_b, float* __restrict__ bm) {
  int b = blockIdx.x;
  int tid = threadIdx.x;

  if (b < B_LN1) {
    // ---- LN1 over real tokens: 2 tokens per block ----
    int sub = tid >> 7, tl = tid & 127;
    long t = (long)b * 2 + sub;                // 0..16383
    const float* xr = x + t * DIM_;
    float v0 = xr[tl], v1 = xr[tl + 128], v2 = xr[tl + 256];
    float s = v0 + v1 + v2, s2 = v0 * v0 + v1 * v1 + v2 * v2;
    for (int off = 32; off; off >>= 1) { s += __shfl_down(s, off); s2 += __shfl_down(s2, off); }
    __shared__ float red[2][4];
    if ((tl & 63) == 0) { red[sub][tl >> 6] = s; red[sub][2 + (tl >> 6)] = s2; }
    __syncthreads();
    float S = red[sub][0] + red[sub][1], S2 = red[sub][2] + red[sub][3];
    float m  = S * (1.f / DIM_);
    float rs = rsqrtf(S2 * (1.f / DIM_) - m * m + EPS_);
    __bf16* orow = xn + t * DIM_;
    orow[tl]       = (__bf16)((v0 - m) * rs * ln1_g[tl]       + ln1_b[tl]);
    orow[tl + 128] = (__bf16)((v1 - m) * rs * ln1_g[tl + 128] + ln1_b[tl + 128]);
    orow[tl + 256] = (__bf16)((v2 - m) * rs * ln1_g[tl + 256] + ln1_b[tl + 256]);
    return;
  }
  b -= B_LN1;
  if (b < B_PADR) {              // shared pad-token row: LN(0-pad) = ln1_b
    for (int i = tid; i < DIM_; i += 256)
      xn[(long)PADROW * DIM_ + i] = (__bf16)ln1_b[i];
    return;
  }
  b -= B_PADR;
  if (b < B_QKV) {               // qkv_w (384x1152) -> wqkv (1152x384)
    int id = b * 256 + tid;
    int k = id % DIM_; int n = id / DIM_;
    wqkv[id] = (__bf16)qkv_w[(long)k * QKVD + n];
    return;
  }
  b -= B_QKV;
  if (b < B_PROJ) {              // proj_w -> wproj^T
    int id = b * 256 + tid;
    int k = id % DIM_; int n = id / DIM_;
    wproj[id] = (__bf16)proj_w[(long)k * DIM_ + n];
    return;
  }
  b -= B_PROJ;
  if (b < B_FC1) {               // fc1_w (384x1536) -> wfc1 (1536x384)
    int id = b * 256 + tid;
    int k = id % DIM_; int n = id / DIM_;
    wfc1[id] = (__bf16)fc1_w[(long)k * HIDD + n];
    return;
  }
  b -= B_FC1;
  if (b < B_FC2) {               // fc2_w (1536x384) -> wfc2 (384x1536)
    int id = b * 256 + tid;
    int k = id % HIDD; int n = id / HIDD;
    wfc2[id] = (__bf16)fc2_w[(long)k * DIM_ + n];
    return;
  }
  b -= B_FC2;
  if (b < B_CONV) {              // conv_w [384][9] -> wconv [9][384]
    int id = b * 256 + tid;
    if (id < 3456) {
      int ch = id / 9, k = id % 9;
      wconv[k * DIM_ + ch] = conv_w[id];
    }
    return;
  }
  b -= B_CONV;
  {                              // bias table bm[12][64][64], mask kk>=49
    int id = b * 256 + tid;
    int h = id >> 12, q = (id >> 6) & 63, kk = id & 63;
    float v;
    if (kk >= NTOK)      v = -1e30f;
    else if (q >= NTOK)  v = 0.f;
    else {
      int idx = abs(q / 7 - kk / 7) * 7 + abs(q % 7 - kk % 7);
      v = attn_b[h * NTOK + idx];
    }
    bm[id] = v;
  }
}

// ---------------------------------------------------------------------------
// Fused depthwise 3x3 conv + BN + LN2. Block = 4 pixels x 96 lanes (384 thr).
// ---------------------------------------------------------------------------
__global__ __launch_bounds__(384) void conv_bn_ln2(
    const float* __restrict__ x1, const float* __restrict__ wT,
    const float* __restrict__ bng, const float* __restrict__ bnb,
    const float* __restrict__ mean, const float* __restrict__ var,
    const float* __restrict__ g2, const float* __restrict__ b2,
    float* __restrict__ x2, __bf16* __restrict__ xln2) {
  int tid = threadIdx.x;
  int p = tid / 96, g = tid % 96;
  int pix = blockIdx.x * 4 + p;            // 0..16383
  int bb = pix >> 12, rc = pix & 4095;
  int r = rc >> 6, c = rc & 63;
  int ch = g << 2;

  f32x4 acc = (f32x4){0.f, 0.f, 0.f, 0.f};
  #pragma unroll
  for (int dr = -1; dr <= 1; dr++) {
    int rr = r + dr;
    if (rr < 0 || rr >= 64) continue;
    #pragma unroll
    for (int dc = -1; dc <= 1; dc++) {
      int cc = c + dc;
      if (cc < 0 || cc >= 64) continue;
      f32x4 xv = *(const f32x4*)(x1 + ((long)bb * 4096 + rr * 64 + cc) * DIM_ + ch);
      f32x4 wv = *(const f32x4*)(wT + ((dr + 1) * 3 + (dc + 1)) * DIM_ + ch);
      acc += xv * wv;
    }
  }

  f32x4 gv = *(const f32x4*)(bng + ch);
  f32x4 vv = *(const f32x4*)(var + ch);
  f32x4 mv = *(const f32x4*)(mean + ch);
  f32x4 bv = *(const f32x4*)(bnb + ch);
  f32x4 y;
  #pragma unroll
  for (int j = 0; j < 4; j++) {
    float sc = gv[j] * rsqrtf(vv[j] + EPS_);
    y[j] = acc[j] * sc + (bv[j] - mv[j] * sc);
  }
  *(f32x4*)(x2 + (long)pix * DIM_ + ch) = y;

  __shared__ float pS[4][96], pS2[4][96], mS[4], rS[4];
  pS[p][g]  = y[0] + y[1] + y[2] + y[3];
  pS2[p][g] = y[0] * y[0] + y[1] * y[1] + y[2] * y[2] + y[3] * y[3];
  __syncthreads();
  if (g < 32) {
    float a  = pS[p][g]  + pS[p][g + 32]  + pS[p][g + 64];
    float a2 = pS2[p][g] + pS2[p][g + 32] + pS2[p][g + 64];
    #pragma unroll
    for (int off = 1; off < 32; off <<= 1) {
      a  += __shfl_xor(a, off);
      a2 += __shfl_xor(a2, off);
    }
    if (g == 0) {
      float m = a * (1.f / DIM_);
      mS[p] = m;
      rS[p] = rsqrtf(a2 * (1.f / DIM_) - m * m + EPS_);
    }
  }
  __syncthreads();
  float m = mS[p], rs = rS[p];
  f32x4 gg = *(const f32x4*)(g2 + ch);
  f32x4 b2v = *(const f32x4*)(b2 + ch);
  bf16x4 ov;
  #pragma unroll
  for (int j = 0; j < 4; j++) ov[j] = (__bf16)((y[j] - m) * rs * gg[j] + b2v[j]);
  *(bf16x4*)(xln2 + (long)pix * DIM_ + ch) = ov;
}

// ---------------------------------------------------------------------------
// MFMA attention, token-gather version. One 64-thread block per (win, head).
// qkv is token-ordered [16385 x 1152]. Window rows are gathered via
// token = bb*4096 + (wy*7+ty)*64 + wx*7+tx; pad / out-of-window -> PADROW.
// Wrong-key columns (t>=49) masked by bm; pad-pixel keys are the shared
// ln1_b-derived row, matching the reference. O is scattered to token order
// (window-reverse fused here); q>=49 and pad-pixel q rows are dropped.
// ---------------------------------------------------------------------------
__global__ __launch_bounds__(64) void attn_mfma(const __bf16* __restrict__ qkv,
                                                const float* __restrict__ bm,
                                                __bf16* __restrict__ o) {
  int blk = blockIdx.x;
  int win = blk / 12, h = blk % 12;
  int bb = win / 100, rem = win % 100;
  int wy = rem / 10, wx = rem % 10;
  int lane = threadIdx.x;
  int quad = lane >> 4, l16 = lane & 15;

  __shared__ __align__(16) __bf16 Vt[32][72];   // Vt[d][kk]
  __shared__ __align__(16) __bf16 P[64][72];    // P[q][kk]

  const __bf16* base = qkv + h * 96;

  // Q (A-operand) / K (B-operand) fragments via token gather
  bf16x8 qf[4], kf[4];
  #pragma unroll
  for (int mt = 0; mt < 4; mt++) {
    int t = mt * 16 + l16;
    int ty = t / 7, tx = t % 7;
    int r = wy * 7 + ty, c = wx * 7 + tx;
    int row = (t < NTOK && r < 64 && c < 64) ? (bb * 4096 + r * 64 + c) : PADROW;
    const __bf16* rp = base + (long)row * QKVD + quad * 8;
    qf[mt] = *(const bf16x8*)(rp);
    kf[mt] = *(const bf16x8*)(rp + 32);
  }
  // V transposed into LDS
  {
    int t = lane;
    int ty = t / 7, tx = t % 7;
    int r = wy * 7 + ty, c = wx * 7 + tx;
    int row = (t < NTOK && r < 64 && c < 64) ? (bb * 4096 + r * 64 + c) : PADROW;
    const __bf16* vp = base + (long)row * QKVD + 64;
    bf16x8 vv[4];
    #pragma unroll
    for (int i = 0; i < 4; i++) vv[i] = *(const bf16x8*)(vp + i * 8);
    #pragma unroll
    for (int i = 0; i < 4; i++)
      #pragma unroll
      for (int j = 0; j < 8; j++) Vt[i * 8 + j][lane] = vv[i][j];
  }

  f32x4 S[4][4];
  #pragma unroll
  for (int i = 0; i < 4; i++)
    #pragma unroll
    for (int j = 0; j < 4; j++) S[i][j] = (f32x4){0.f, 0.f, 0.f, 0.f};
  #pragma unroll
  for (int mt = 0; mt < 4; mt++)
    #pragma unroll
    for (int nt = 0; nt < 4; nt++)
      S[mt][nt] = __builtin_amdgcn_mfma_f32_16x16x32_bf16(qf[mt], kf[nt], S[mt][nt], 0, 0, 0);

  const float* bmh = bm + h * 4096;
  #pragma unroll
  for (int mt = 0; mt < 4; mt++)
    #pragma unroll
    for (int r = 0; r < 4; r++) {
      int q = mt * 16 + quad * 4 + r;
      #pragma unroll
      for (int nt = 0; nt < 4; nt++)
        S[mt][nt][r] = S[mt][nt][r] * SCALE_ + bmh[q * 64 + nt * 16 + l16];
    }

  #pragma unroll
  for (int mt = 0; mt < 4; mt++)
    #pragma unroll
    for (int r = 0; r < 4; r++) {
      float mx = fmaxf(fmaxf(S[mt][0][r], S[mt][1][r]), fmaxf(S[mt][2][r], S[mt][3][r]));
      #pragma unroll
      for (int off = 1; off < 16; off <<= 1) mx = fmaxf(mx, __shfl_xor(mx, off));
      float sum = 0.f;
      #pragma unroll
      for (int nt = 0; nt < 4; nt++) {
        float e = __expf(S[mt][nt][r] - mx);
        S[mt][nt][r] = e;
        sum += e;
      }
      #pragma unroll
      for (int off = 1; off < 16; off <<= 1) sum += __shfl_xor(sum, off);
      float inv = 1.f / sum;
      #pragma unroll
      for (int nt = 0; nt < 4; nt++) S[mt][nt][r] *= inv;
    }

  #pragma unroll
  for (int mt = 0; mt < 4; mt++)
    #pragma unroll
    for (int r = 0; r < 4; r++) {
      int q = mt * 16 + quad * 4 + r;
      #pragma unroll
      for (int nt = 0; nt < 4; nt++)
        P[q][nt * 16 + l16] = (__bf16)S[mt][nt][r];
    }
  __syncthreads();

  f32x4 O[4][2];
  #pragma unroll
  for (int i = 0; i < 4; i++)
    #pragma unroll
    for (int j = 0; j < 2; j++) O[i][j] = (f32x4){0.f, 0.f, 0.f, 0.f};
  #pragma unroll
  for (int kt = 0; kt < 2; kt++) {
    bf16x8 pf[4], vf[2];
    #pragma unroll
    for (int mt = 0; mt < 4; mt++)
      pf[mt] = *(const bf16x8*)(&P[mt * 16 + l16][kt * 32 + quad * 8]);
    #pragma unroll
    for (int nt = 0; nt < 2; nt++)
      vf[nt] = *(const bf16x8*)(&Vt[nt * 16 + l16][kt * 32 + quad * 8]);
    #pragma unroll
    for (int mt = 0; mt < 4; mt++)
      #pragma unroll
      for (int nt = 0; nt < 2; nt++)
        O[mt][nt] = __builtin_amdgcn_mfma_f32_16x16x32_bf16(pf[mt], vf[nt], O[mt][nt], 0, 0, 0);
  }

  // scatter O to token order (window-reverse fused); drop pad/q>=49 rows
  #pragma unroll
  for (int mt = 0; mt < 4; mt++)
    #pragma unroll
    for (int r = 0; r < 4; r++) {
      int q = mt * 16 + quad * 4 + r;
      if (q < NTOK) {
        int ty = q / 7, tx = q % 7;
        int rr = wy * 7 + ty, cc = wx * 7 + tx;
        if (rr < 64 && cc < 64) {
          __bf16* ob = o + ((long)bb * 4096 + rr * 64 + cc) * DIM_ + h * 32;
          #pragma unroll
          for (int nt = 0; nt < 2; nt++)
            ob[nt * 16 + l16] = (__bf16)O[mt][nt][r];
        }
      }
    }
}

// ---------------------------------------------------------------------------
// bf16 MFMA GEMM (round-5 structure). C(MxN) = A(MxK) @ Bt(NxK)^T.
// Tile 128 x TN, 4 waves (2x2), BK=32 LDS staging via global_load_lds(16B).
// MODE 0: bf16 out = acc + bias
// MODE 2: bf16 out = gelu_fast(acc + bias)
// MODE 3: f32 out = acc + bias + res
// ---------------------------------------------------------------------------
template <int MODE, int TN>
__global__ void __launch_bounds__(256)
gemm_bf16(const __bf16* __restrict__ A, const __bf16* __restrict__ Bt,
          const float* __restrict__ bias, int K, int N,
          float* __restrict__ outf, __bf16* __restrict__ outb,
          const float* __restrict__ res) {
  constexpr int NT = TN / 32;
  __shared__ __align__(16) __bf16 sA[128 * 32];
  __shared__ __align__(16) __bf16 sB[TN * 32];
  int tid = threadIdx.x, lane = tid & 63, wid = tid >> 6;
  int wm = wid >> 1, wn = wid & 1;
  int quad = lane >> 4, l16 = lane & 15;
  long tileM = (long)blockIdx.x * 128;
  long tileN = (long)blockIdx.y * TN;

  f32x4 acc[4][NT];
  #pragma unroll
  for (int i = 0; i < 4; i++)
    #pragma unroll
    for (int j = 0; j < NT; j++) acc[i][j] = (f32x4){0.f, 0.f, 0.f, 0.f};

  int rr = wid * 16 + (lane >> 2);
  const __bf16* gA = A  + (tileM + rr) * (long)K + ((lane & 3) << 3);
  const __bf16* gB = Bt + (tileN + rr) * (long)K + ((lane & 3) << 3);
  const long rowskip = 64 * (long)K;

  for (int k0 = 0; k0 < K; k0 += 32) {
    gload_lds16(gA + k0,           sA + (wid << 9));
    gload_lds16(gA + k0 + rowskip, sA + ((wid + 4) << 9));
    gload_lds16(gB + k0,           sB + (wid << 9));
    if (TN == 128)
      gload_lds16(gB + k0 + rowskip, sB + ((wid + 4) << 9));
    __syncthreads();
    bf16x8 af[4], bfr[NT];
    #pragma unroll
    for (int mt = 0; mt < 4; mt++)
      af[mt] = *(const bf16x8*)(sA + ((wm * 64 + mt * 16 + l16) << 5) + (quad << 3));
    #pragma unroll
    for (int nt = 0; nt < NT; nt++)
      bfr[nt] = *(const bf16x8*)(sB + ((wn * (TN / 2) + nt * 16 + l16) << 5) + (quad << 3));
    #pragma unroll
    for (int mt = 0; mt < 4; mt++)
      #pragma unroll
      for (int nt = 0; nt < NT; nt++)
        acc[mt][nt] = __builtin_amdgcn_mfma_f32_16x16x32_bf16(af[mt], bfr[nt], acc[mt][nt], 0, 0, 0);
    __syncthreads();
  }

  float bcol[NT];
  #pragma unroll
  for (int nt = 0; nt < NT; nt++) bcol[nt] = bias[tileN + wn * (TN / 2) + nt * 16 + l16];

  #pragma unroll
  for (int mt = 0; mt < 4; mt++) {
    #pragma unroll
    for (int r = 0; r < 4; r++) {
      long row = tileM + wm * 64 + mt * 16 + quad * 4 + r;
      if (MODE == 0) {
        __bf16* orow = outb + row * (long)N;
        #pragma unroll
        for (int nt = 0; nt < NT; nt++)
          orow[tileN + wn * (TN / 2) + nt * 16 + l16] = (__bf16)(acc[mt][nt][r] + bcol[nt]);
      } else if (MODE == 2) {
        __bf16* orow = outb + row * (long)N;
        #pragma unroll
        for (int nt = 0; nt < NT; nt++) {
          float v = acc[mt][nt][r] + bcol[nt];
          orow[tileN + wn * (TN / 2) + nt * 16 + l16] = (__bf16)gelu_fast(v);
        }
      } else {
        float* orow = outf + row * (long)N;
        const float* rrow = res + row * (long)N;
        #pragma unroll
        for (int nt = 0; nt < NT; nt++) {
          long col = tileN + wn * (TN / 2) + nt * 16 + l16;
          orow[col] = acc[mt][nt][r] + bcol[nt] + rrow[col];
        }
      }
    }
  }
}

// ---------------------------------------------------------------------------
extern "C" void kernel_launch(void* const* d_in, const int* in_sizes, int n_in,
                              void* d_out, int out_size, void* d_ws, size_t ws_size,
                              hipStream_t stream) {
  const float* x       = (const float*)d_in[0];
  const float* ln1_g   = (const float*)d_in[1];
  const float* ln1_b   = (const float*)d_in[2];
  const float* qkv_w   = (const float*)d_in[3];
  const float* qkv_b   = (const float*)d_in[4];
  const float* proj_w  = (const float*)d_in[5];
  const float* proj_b  = (const float*)d_in[6];
  const float* attn_b  = (const float*)d_in[7];
  const float* conv_w  = (const float*)d_in[8];
  const float* bn_g    = (const float*)d_in[9];
  const float* bn_b    = (const float*)d_in[10];
  const float* bn_mean = (const float*)d_in[11];
  const float* bn_var  = (const float*)d_in[12];
  const float* ln2_g   = (const float*)d_in[13];
  const float* ln2_b   = (const float*)d_in[14];
  const float* fc1_w   = (const float*)d_in[15];
  const float* fc1_b   = (const float*)d_in[16];
  const float* fc2_w   = (const float*)d_in[17];
  const float* fc2_b   = (const float*)d_in[18];

  // workspace layout (token-compact; aliasing):
  char* p = (char*)d_ws;
  __bf16* WQKV = (__bf16*)p;  p += 884736;     // 1152x384
  __bf16* WPROJ = (__bf16*)p; p += 294912;     // 384x384
  __bf16* WFC1 = (__bf16*)p;  p += 1179648;    // 1536x384
  __bf16* WFC2 = (__bf16*)p;  p += 1179648;    // 384x1536
  float*  WCONV = (float*)p;  p += 13824;      // 9x384
  char* region = p;           p += 63307776;
  float* X1 = (float*)p;      p += 25165824;
  float* X2 = (float*)p;      p += 25165824;
  __bf16* XN   = (__bf16*)region;                 // 16512x384 (dead after qkv)
  __bf16* QKVB = (__bf16*)(region + 12681216);    // 16512x1152
  __bf16* OBUF = (__bf16*)(region + 50724864);    // 16384x384 (token order)
  __bf16* XLN2 = (__bf16*)region;                 // 16384x384 (aliases XN, dead)
  __bf16* H1   = (__bf16*)(region + 12681216);    // 16384x1536 (aliases QKVB+OBUF, dead)
  float*  BM   = X1;                              // 12x64x64 bias table; X1 not yet live
  float* OUT = (float*)d_out;

  prep_all<<<B_TOTAL, 256, 0, stream>>>(x, ln1_g, ln1_b, XN,
                                        qkv_w, WQKV, proj_w, WPROJ,
                                        fc1_w, WFC1, fc2_w, WFC2,
                                        conv_w, WCONV, attn_b, BM);

  // qkv: M=16512 (tokens + pad row), K=384, N=1152
  gemm_bf16<0, 128><<<dim3(MQKV / 128, QKVD / 128), 256, 0, stream>>>(
      XN, WQKV, qkv_b, DIM_, QKVD, nullptr, QKVB, nullptr);

  attn_mfma<<<NWIN * 12, 64, 0, stream>>>(QKVB, BM, OBUF);

  // proj: M=16384, K=384, N=384; X1 = x + OBUF@Wp + b (plain rows now)
  gemm_bf16<3, 64><<<dim3(TOKENS / 128, DIM_ / 64), 256, 0, stream>>>(
      OBUF, WPROJ, proj_b, DIM_, DIM_, X1, nullptr, x);

  conv_bn_ln2<<<TOKENS / 4, 384, 0, stream>>>(X1, WCONV, bn_g, bn_b, bn_mean, bn_var,
                                              ln2_g, ln2_b, X2, XLN2);

  // fc1: M=16384, K=384, N=1536, gelu
  gemm_bf16<2, 128><<<dim3(TOKENS / 128, HIDD / 128), 256, 0, stream>>>(
      XLN2, WFC1, fc1_b, DIM_, HIDD, nullptr, H1, nullptr);

  // fc2: M=16384, K=1536, N=384, + residual -> OUT
  gemm_bf16<3, 64><<<dim3(TOKENS / 128, DIM_ / 64), 256, 0, stream>>>(
      H1, WFC2, fc2_b, HIDD, DIM_, OUT, nullptr, X2);
}